// Round 4
// baseline (264.981 us; speedup 1.0000x reference)
//
#include <hip/hip_runtime.h>

// HexConv2d implicit GEMM, bf16 MFMA 16x16x32.
// v4: 256o x 64pix blocks (acc 4x4/wave, ~155 regs -> 3 waves/SIMD), grid 39x32=1248
// for small tail; double-buffered global_load_lds staging in pitch-50 padded pixel
// space (all tap edge cases = natural zero reads); A (weights) fragment-packed in L2.
// Prep: coalesced masked transpose to pixel-major bf16 xb (pixel-pair dword reads).

typedef __attribute__((ext_vector_type(8))) short short8;
typedef __attribute__((ext_vector_type(4))) short short4v;
typedef __attribute__((ext_vector_type(4))) float floatx4;

#define NPIX   2401
#define W50    50
#define PREAL  2450      // 49 rows * 50
#define XBLEAD 56
#define XBROWS 2672      // padded rows per batch: [-56, 2616)
#define NT4    39        // 39*64 = 2496 >= 2450
#define NSEG4  11        // 176 window rows: [P0-56, P0+120)
#define BUFB4  (NSEG4*1024)
#define XB3_BYTES ((size_t)32*XBROWS*256*2)   // 43,778,048
#define WP_BYTES  917504ULL
#define WS_NEED3  (XB3_BYTES + WP_BYTES)

__device__ __forceinline__ unsigned short f2bf(float f) {
  unsigned u = __builtin_bit_cast(unsigned, f);
  u += 0x7fffu + ((u >> 16) & 1u);          // RNE
  return (unsigned short)(u >> 16);
}

// ---------------- prep: W[o,c,n] fp32 -> bf16 MFMA-A fragment order ----------------
// frag f = ((n*8+kc)*16+ot): lane l holds 8 bf16: W[ot*16+(l&15)][kc*32+(l>>4)*8+j][n]
__global__ void prep_w_kernel(const float* __restrict__ w, unsigned short* __restrict__ wp) {
  int t = blockIdx.x * 256 + threadIdx.x;   // 0..57343
  int l  = t & 63;
  int ot = (t >> 6) & 15;
  int kc = (t >> 10) & 7;
  int n  = t >> 13;
  int o  = ot * 16 + (l & 15);
  int cb = kc * 32 + ((l >> 4) * 8);
  const float* src = w + (size_t)(o * 256 + cb) * 7 + n;
  short8 pk;
#pragma unroll
  for (int j = 0; j < 8; ++j) pk[j] = (short)f2bf(src[j * 7]);
  ((short8*)wp)[t] = pk;
}

// ---------------- prep: zero all pad rows of xb ----------------
__global__ void zero_pads(unsigned short* __restrict__ xb) {
  int idx = blockIdx.x * 256 + threadIdx.x;   // 32*2672*32 threads
  int c16 = idx & 31;
  int rb  = idx >> 5;
  int row = rb % XBROWS;
  int b   = rb / XBROWS;
  int p   = row - XBLEAD;
  bool pad = (p < 0) || (p >= PREAL) || (p % W50 == 49);
  if (pad) {
    short8 z = {0,0,0,0,0,0,0,0};
    *(short8*)(xb + ((size_t)b * XBROWS + row) * 256 + c16 * 8) = z;
  }
}

// ---------------- prep: x [b][c][2401] fp32 -> xb [b][row][256c] bf16 (masked) ------
__global__ __launch_bounds__(256)
void prep_x4(const float* __restrict__ x, unsigned short* __restrict__ xb) {
  __shared__ unsigned short t[64][68];      // [ch_local][pix_local], pitch 68 shorts
  const int tid = threadIdx.x;
  const int span = blockIdx.x, cg = blockIdx.y, b = blockIdx.z;
  const int s0 = span * 64;
  // ---- phase 1: load fp32 (coalesced float4), mask+convert, write [ch][pix] ----
  {
    const int chl = tid >> 2, i4 = tid & 3;
    const float* src = x + ((size_t)(b * 256 + cg * 64 + chl)) * NPIX;
    const int rbase = s0 + i4 * 16;
#pragma unroll
    for (int it = 0; it < 4; ++it) {
      int r = rbase + it * 4;
      float vv[4] = {0.f, 0.f, 0.f, 0.f};
      if (r + 3 < NPIX) {
        float4 v = *(const float4*)(src + r);
        vv[0] = v.x; vv[1] = v.y; vv[2] = v.z; vv[3] = v.w;
      } else {
#pragma unroll
        for (int e = 0; e < 4; ++e) if (r + e < NPIX) vv[e] = src[r + e];
      }
      short4v u = {0, 0, 0, 0};
#pragma unroll
      for (int e = 0; e < 4; ++e) {
        int re = r + e;
        unsigned short uu = 0;
        if (re < NPIX) {
          int h = re / 49, w = re - h * 49, s = h + w;
          if (s >= 24 && s <= 72) uu = f2bf(vv[e]);
        }
        u[e] = (short)uu;
      }
      *(short4v*)&t[chl][i4 * 16 + it * 4] = u;
    }
  }
  __syncthreads();
  // ---- phase 2: pixel-pair dword reads, repack, 16B stores to [pix][ch] ----
  const int pp = tid >> 3;   // pixel pair 0..31
  const int co = tid & 7;    // channel octet 0..7
  unsigned d[8];
#pragma unroll
  for (int k = 0; k < 8; ++k) d[k] = *(const unsigned*)&t[co * 8 + k][pp * 2];
  uint4 lo, hi;
  {
    unsigned l0[4], h0[4];
#pragma unroll
    for (int m = 0; m < 4; ++m) {
      unsigned a = d[2 * m], bq = d[2 * m + 1];
      l0[m] = (a & 0xffffu) | (bq << 16);
      h0[m] = (a >> 16) | (bq & 0xffff0000u);
    }
    lo = make_uint4(l0[0], l0[1], l0[2], l0[3]);
    hi = make_uint4(h0[0], h0[1], h0[2], h0[3]);
  }
  const int r_lo = s0 + pp * 2, r_hi = r_lo + 1;
  if (r_lo < NPIX) {
    int prow = r_lo + r_lo / 49 + XBLEAD;
    *(uint4*)(xb + ((size_t)b * XBROWS + prow) * 256 + cg * 64 + co * 8) = lo;
  }
  if (r_hi < NPIX) {
    int prow = r_hi + r_hi / 49 + XBLEAD;
    *(uint4*)(xb + ((size_t)b * XBROWS + prow) * 256 + cg * 64 + co * 8) = hi;
  }
}

// ---------------- main v4 ----------------
__global__ __launch_bounds__(256, 3)
void hexconv_v4(const unsigned short* __restrict__ xb,
                const unsigned short* __restrict__ wp,
                const float* __restrict__ bias,
                float* __restrict__ out) {
  __shared__ __attribute__((aligned(16))) unsigned char smem[2 * BUFB4];  // 22528 B

  const int tid  = threadIdx.x;
  const int lane = tid & 63;
  const int wv   = tid >> 6;
  const int col  = lane & 15;
  const int quad = lane >> 4;

  const int pt = blockIdx.x;          // 0..38
  const int b  = blockIdx.y;
  const int P0 = pt * 64;
  const int phase = (pt + b * 3) & 7;

  // tap offsets in pitch-50 padded space
  const int OFF[7] = {0, 50, 1, -49, -50, -1, 49};

  // B-frag LDS base addresses (kc/j-invariant; j adds j*1024; swizzle j-invariant)
  int ba[7];
#pragma unroll
  for (int n = 0; n < 7; ++n) {
    int r0 = col + 56 + OFF[n];              // 6..121
    int r64 = r0 << 6;
    ba[n] = (r64 + quad * 16) ^ ((r64 >> 3) & 0x30);
  }

  // staging: lane l covers window row 16s+(l>>2), LDS part l&3, global part swizzled
  const int gpart = (lane & 3) ^ ((lane >> 3) & 3);
  const char* gsrc0 = (const char*)(xb + ((size_t)b * XBROWS + (size_t)P0) * 256)
                      + (lane >> 2) * 512 + gpart * 16;

  auto stage = [&](int buf, int kc) {
    char* ldsb = (char*)smem + buf * BUFB4;
    for (int s = wv; s < NSEG4; s += 4)
      __builtin_amdgcn_global_load_lds(
          (const __attribute__((address_space(1))) unsigned int*)(gsrc0 + (size_t)s * 8192 + kc * 64),
          (__attribute__((address_space(3))) unsigned int*)(ldsb + s * 1024), 16, 0, 0);
  };

  const char* wbase = (const char*)wp + (size_t)(wv * 4) * 1024 + lane * 16;

  floatx4 acc[4][4];
#pragma unroll
  for (int ii = 0; ii < 4; ++ii)
#pragma unroll
    for (int j = 0; j < 4; ++j) acc[ii][j] = (floatx4){0.f, 0.f, 0.f, 0.f};

  stage(0, phase);
  __syncthreads();

  for (int i = 0; i < 8; ++i) {
    const int kc  = (i + phase) & 7;
    const int kcn = (i + 1 + phase) & 7;
    if (i < 7) stage((i + 1) & 1, kcn);
    const char* bufp = (const char*)smem + (i & 1) * BUFB4;
#pragma unroll
    for (int n = 0; n < 7; ++n) {
      short8 af[4];
#pragma unroll
      for (int ii = 0; ii < 4; ++ii)
        af[ii] = *(const short8*)(wbase + ((size_t)((n * 8 + kc) * 16 + ii)) * 1024);
      short8 bf[4];
#pragma unroll
      for (int j = 0; j < 4; ++j)
        bf[j] = *(const short8*)(bufp + ba[n] + j * 1024);
#pragma unroll
      for (int ii = 0; ii < 4; ++ii)
#pragma unroll
        for (int j = 0; j < 4; ++j)
          acc[ii][j] = __builtin_amdgcn_mfma_f32_16x16x32_bf16(af[ii], bf[j], acc[ii][j], 0, 0, 0);
    }
    __syncthreads();
  }

  // epilogue: D[row=quad*4+rr][col]; o = wv*64+ii*16+quad*4+rr, padded pix = P0+j*16+col
  const int ob = wv * 64;
  floatx4 bv[4];
#pragma unroll
  for (int ii = 0; ii < 4; ++ii)
    bv[ii] = *(const floatx4*)(bias + ob + ii * 16 + quad * 4);

#pragma unroll
  for (int j = 0; j < 4; ++j) {
    int p = P0 + j * 16 + col;
    int h = p / W50;
    int w = p - h * W50;
    if (w >= 49 || p >= PREAL) continue;
    bool m = (h + w >= 24) && (h + w <= 72);
    size_t ridx = (size_t)h * 49 + w;
#pragma unroll
    for (int ii = 0; ii < 4; ++ii) {
      float* dst = out + ((size_t)(b * 256 + ob + ii * 16 + quad * 4)) * NPIX + ridx;
#pragma unroll
      for (int rr = 0; rr < 4; ++rr) {
        float v = m ? (acc[ii][j][rr] + bv[ii][rr]) : 0.f;
        dst[(size_t)rr * NPIX] = v;
      }
    }
  }
}

// ---------------- fallback v1 (ws too small) ----------------
#define PITCH  40
#define V1WIN  168
#define V1ZROW 168
__global__ __launch_bounds__(256)
void hexconv_v1(const float* __restrict__ x,
                const unsigned short* __restrict__ wp,
                const float* __restrict__ bias,
                float* __restrict__ out) {
  __shared__ unsigned short sm[(V1ZROW + 2) * PITCH];
  const int tid = threadIdx.x, lane = tid & 63, wv = tid >> 6;
  const int col = lane & 15, quad = lane >> 4;
  const int pt = blockIdx.x, b = blockIdx.y;
  const int P0 = pt * 64, win_start = P0 - 52;
  if (tid < PITCH * 2) sm[V1ZROW * PITCH + tid] = 0;
  const int OFF[7] = {0, 49, 1, -48, -49, -1, 48};
  const int DXP = (1 << 2) | (1 << 3), DXN = (1 << 5) | (1 << 6);
  int baddr[4][7];
#pragma unroll
  for (int j = 0; j < 4; ++j) {
    int pix = P0 + j * 16 + col;
    int wj = pix % 49;
    int rowbase = pix - win_start;
#pragma unroll
    for (int n = 0; n < 7; ++n) {
      bool bad = (((DXP >> n) & 1) && wj == 48) || (((DXN >> n) & 1) && wj == 0);
      int row = bad ? V1ZROW : (rowbase + OFF[n]);
      baddr[j][n] = row * (PITCH * 2) + quad * 16;
    }
  }
  int sp[3], sgp[3]; bool sok[3];
#pragma unroll
  for (int pi = 0; pi < 3; ++pi) {
    int p = lane + pi * 64, gp = win_start + p;
    sp[pi] = p; sgp[pi] = gp;
    bool hm = false;
    if (gp >= 0 && gp < NPIX) { int h = gp / 49, w = gp - h * 49, s = h + w; hm = (s >= 24 && s <= 72); }
    sok[pi] = (p < V1WIN) && hm;
  }
  floatx4 acc[4][4];
#pragma unroll
  for (int i = 0; i < 4; ++i)
#pragma unroll
    for (int j = 0; j < 4; ++j) acc[i][j] = (floatx4){0.f, 0.f, 0.f, 0.f};
  const short8* wpv = (const short8*)wp;
  const int wslot = wv * 4;
  for (int kc = 0; kc < 8; ++kc) {
    __syncthreads();
#pragma unroll
    for (int ci = 0; ci < 8; ++ci) {
      int c = ci * 4 + wv;
      const float* src = x + ((size_t)(b * 256 + kc * 32 + c)) * NPIX;
#pragma unroll
      for (int pi = 0; pi < 3; ++pi) {
        if (sp[pi] < V1WIN) {
          float v = sok[pi] ? src[sgp[pi]] : 0.f;
          sm[sp[pi] * PITCH + c] = f2bf(v);
        }
      }
    }
    __syncthreads();
#pragma unroll
    for (int n = 0; n < 7; ++n) {
      short8 af[4];
#pragma unroll
      for (int i = 0; i < 4; ++i)
        af[i] = wpv[((size_t)((n * 8 + kc) * 16 + wslot + i)) * 64 + lane];
      short8 bf[4];
#pragma unroll
      for (int j = 0; j < 4; ++j)
        bf[j] = *(const short8*)((const char*)sm + baddr[j][n]);
#pragma unroll
      for (int i = 0; i < 4; ++i)
#pragma unroll
        for (int j = 0; j < 4; ++j)
          acc[i][j] = __builtin_amdgcn_mfma_f32_16x16x32_bf16(af[i], bf[j], acc[i][j], 0, 0, 0);
    }
  }
  const int ob = wv * 64;
  floatx4 bv[4];
#pragma unroll
  for (int i = 0; i < 4; ++i)
    bv[i] = *(const floatx4*)(bias + ob + i * 16 + quad * 4);
#pragma unroll
  for (int j = 0; j < 4; ++j) {
    int pix = P0 + j * 16 + col;
    if (pix >= NPIX) continue;
    int h = pix / 49, w = pix - h * 49;
    bool m = (h + w >= 24 && h + w <= 72);
#pragma unroll
    for (int i = 0; i < 4; ++i) {
      int o = ob + i * 16 + quad * 4;
      float* dst = out + ((size_t)(b * 256 + o)) * NPIX + pix;
#pragma unroll
      for (int r = 0; r < 4; ++r) {
        float v = m ? (acc[i][j][r] + bv[i][r]) : 0.f;
        dst[(size_t)r * NPIX] = v;
      }
    }
  }
}

extern "C" void kernel_launch(void* const* d_in, const int* in_sizes, int n_in,
                              void* d_out, int out_size, void* d_ws, size_t ws_size,
                              hipStream_t stream) {
  const float* x    = (const float*)d_in[0];   // [32,256,49,49]
  const float* w    = (const float*)d_in[1];   // [256,256,7]
  const float* bias = (const float*)d_in[2];   // [256]
  float* out = (float*)d_out;

  if (ws_size >= WS_NEED3) {
    unsigned short* xb = (unsigned short*)d_ws;
    unsigned short* wp = (unsigned short*)((char*)d_ws + XB3_BYTES);
    zero_pads<<<(32 * XBROWS * 32) / 256, 256, 0, stream>>>(xb);
    prep_w_kernel<<<224, 256, 0, stream>>>(w, wp);
    prep_x4<<<dim3(38, 4, 32), 256, 0, stream>>>(x, xb);
    hexconv_v4<<<dim3(NT4, 32), 256, 0, stream>>>(xb, wp, bias, out);
  } else {
    unsigned short* wp = (unsigned short*)d_ws;
    prep_w_kernel<<<224, 256, 0, stream>>>(w, wp);
    hexconv_v1<<<dim3(38, 32), 256, 0, stream>>>(x, wp, bias, out);
  }
}

// Round 5
// 244.219 us; speedup vs baseline: 1.0850x; 1.0850x over previous
//
#include <hip/hip_runtime.h>

// HexConv2d implicit GEMM, bf16 MFMA 16x16x32.
// v5: v3 shape (256o x 128pix, acc 4x8/wave, 2 waves/SIMD, grid 20x32) with the
// K-pipeline coarsened to 2-kc stages: double-buffered global_load_lds (30KB/buf),
// 4 barriers/block, each barrier's vmcnt(0) drain covered by ~2150 cyc of MFMA.
// Pitch-50 padded pixel space (all tap edge cases = natural zero reads); weights
// fragment-packed in L2. Prep: compact pad-zeroing + coalesced masked transpose.

typedef __attribute__((ext_vector_type(8))) short short8;
typedef __attribute__((ext_vector_type(4))) short short4v;
typedef __attribute__((ext_vector_type(4))) float floatx4;

#define NPIX   2401
#define W50    50
#define PREAL  2450      // 49 rows * 50
#define XBLEAD 56
#define XBROWS 2672      // padded rows per batch: [-56, 2616)
#define PT5    128       // pixels per block
#define NT5    20        // 20*128 = 2560 >= 2450
#define NSEG5  15        // 240 window rows: [P0-56, P0+184)
#define BUF5   (2*NSEG5*1024)                 // 30720 B per buffer (2 kc)
#define XB3_BYTES ((size_t)32*XBROWS*256*2)   // 43,778,048
#define WP_BYTES  917504ULL
#define WS_NEED3  (XB3_BYTES + WP_BYTES)
#define NPADROW 271      // 56 apron + 49 col-49 + 166 tail rows per batch

__device__ __forceinline__ unsigned short f2bf(float f) {
  unsigned u = __builtin_bit_cast(unsigned, f);
  u += 0x7fffu + ((u >> 16) & 1u);          // RNE
  return (unsigned short)(u >> 16);
}

// ---------------- prep: W[o,c,n] fp32 -> bf16 MFMA-A fragment order ----------------
// frag f = ((n*8+kc)*16+ot): lane l holds 8 bf16: W[ot*16+(l&15)][kc*32+(l>>4)*8+j][n]
__global__ void prep_w_kernel(const float* __restrict__ w, unsigned short* __restrict__ wp) {
  int t = blockIdx.x * 256 + threadIdx.x;   // 0..57343
  int l  = t & 63;
  int ot = (t >> 6) & 15;
  int kc = (t >> 10) & 7;
  int n  = t >> 13;
  int o  = ot * 16 + (l & 15);
  int cb = kc * 32 + ((l >> 4) * 8);
  const float* src = w + (size_t)(o * 256 + cb) * 7 + n;
  short8 pk;
#pragma unroll
  for (int j = 0; j < 8; ++j) pk[j] = (short)f2bf(src[j * 7]);
  ((short8*)wp)[t] = pk;
}

// ---------------- prep: zero only the pad rows of xb (compact) ----------------
__global__ void zero_pads5(unsigned short* __restrict__ xb) {
  int idx = blockIdx.x * 256 + threadIdx.x;   // 32*271*32 = 277,504 threads
  if (idx >= 32 * NPADROW * 32) return;
  int c16 = idx & 31;
  int rr  = idx >> 5;
  int pr  = rr % NPADROW;
  int b   = rr / NPADROW;
  int row;
  if (pr < 56)        row = pr;                          // leading apron
  else if (pr < 105)  row = 105 + 50 * (pr - 56);        // col-49 pad rows
  else                row = 2506 + (pr - 105);           // trailing apron
  short8 z = {0,0,0,0,0,0,0,0};
  *(short8*)(xb + ((size_t)b * XBROWS + row) * 256 + c16 * 8) = z;
}

// ---------------- prep: x [b][c][2401] fp32 -> xb [b][row][256c] bf16 (masked) ------
__global__ __launch_bounds__(256)
void prep_x4(const float* __restrict__ x, unsigned short* __restrict__ xb) {
  __shared__ unsigned short t[64][68];      // [ch_local][pix_local]
  const int tid = threadIdx.x;
  const int span = blockIdx.x, cg = blockIdx.y, b = blockIdx.z;
  const int s0 = span * 64;
  {
    const int chl = tid >> 2, i4 = tid & 3;
    const float* src = x + ((size_t)(b * 256 + cg * 64 + chl)) * NPIX;
    const int rbase = s0 + i4 * 16;
#pragma unroll
    for (int it = 0; it < 4; ++it) {
      int r = rbase + it * 4;
      float vv[4] = {0.f, 0.f, 0.f, 0.f};
      if (r + 3 < NPIX) {
        float4 v = *(const float4*)(src + r);
        vv[0] = v.x; vv[1] = v.y; vv[2] = v.z; vv[3] = v.w;
      } else {
#pragma unroll
        for (int e = 0; e < 4; ++e) if (r + e < NPIX) vv[e] = src[r + e];
      }
      short4v u = {0, 0, 0, 0};
#pragma unroll
      for (int e = 0; e < 4; ++e) {
        int re = r + e;
        unsigned short uu = 0;
        if (re < NPIX) {
          int h = re / 49, w = re - h * 49, s = h + w;
          if (s >= 24 && s <= 72) uu = f2bf(vv[e]);
        }
        u[e] = (short)uu;
      }
      *(short4v*)&t[chl][i4 * 16 + it * 4] = u;
    }
  }
  __syncthreads();
  const int pp = tid >> 3;   // pixel pair 0..31
  const int co = tid & 7;    // channel octet 0..7
  unsigned d[8];
#pragma unroll
  for (int k = 0; k < 8; ++k) d[k] = *(const unsigned*)&t[co * 8 + k][pp * 2];
  uint4 lo, hi;
  {
    unsigned l0[4], h0[4];
#pragma unroll
    for (int m = 0; m < 4; ++m) {
      unsigned a = d[2 * m], bq = d[2 * m + 1];
      l0[m] = (a & 0xffffu) | (bq << 16);
      h0[m] = (a >> 16) | (bq & 0xffff0000u);
    }
    lo = make_uint4(l0[0], l0[1], l0[2], l0[3]);
    hi = make_uint4(h0[0], h0[1], h0[2], h0[3]);
  }
  const int r_lo = s0 + pp * 2, r_hi = r_lo + 1;
  if (r_lo < NPIX) {
    int prow = r_lo + r_lo / 49 + XBLEAD;
    *(uint4*)(xb + ((size_t)b * XBROWS + prow) * 256 + cg * 64 + co * 8) = lo;
  }
  if (r_hi < NPIX) {
    int prow = r_hi + r_hi / 49 + XBLEAD;
    *(uint4*)(xb + ((size_t)b * XBROWS + prow) * 256 + cg * 64 + co * 8) = hi;
  }
}

// ---------------- main v5 ----------------
__global__ __launch_bounds__(256, 2)
void hexconv_v5(const unsigned short* __restrict__ xb,
                const unsigned short* __restrict__ wp,
                const float* __restrict__ bias,
                float* __restrict__ out) {
  __shared__ __attribute__((aligned(16))) unsigned char smem[2 * BUF5];  // 61440 B

  const int tid  = threadIdx.x;
  const int lane = tid & 63;
  const int wv   = tid >> 6;
  const int col  = lane & 15;
  const int quad = lane >> 4;

  const int pt = blockIdx.x;          // 0..19
  const int b  = blockIdx.y;
  const int P0 = pt * PT5;
  const int phase = ((pt + b) & 3) * 2;

  // tap offsets in pitch-50 padded space
  const int OFF[7] = {0, 50, 1, -49, -50, -1, 49};

  // B-frag LDS base addresses (kc/j-invariant; j adds j*1024 = 16 rows)
  int ba[7];
#pragma unroll
  for (int n = 0; n < 7; ++n) {
    int r0 = col + 56 + OFF[n];              // 6..121
    int r64 = r0 << 6;
    ba[n] = (r64 + quad * 16) ^ ((r64 >> 3) & 0x30);
  }

  // staging: within a seg, lane l covers row 16s+(l>>2), LDS part l&3 (HW-forced),
  // global part swizzled so compute-side XOR lands conflict-free
  const int gpart = (lane & 3) ^ ((lane >> 3) & 3);
  const char* gsrc0 = (const char*)(xb + ((size_t)b * XBROWS + (size_t)P0) * 256)
                      + (lane >> 2) * 512 + gpart * 16;

  // stage 2 kc (kc0, kc0+... both within one buffer): 30 segs split over 4 waves
  auto stage2 = [&](int buf, int kc0) {
    char* ldsb = (char*)smem + buf * BUF5;
    for (int u = wv; u < 2 * NSEG5; u += 4) {
      int kk = (u >= NSEG5) ? 1 : 0;
      int s  = u - kk * NSEG5;
      __builtin_amdgcn_global_load_lds(
          (const __attribute__((address_space(1))) unsigned int*)
              (gsrc0 + (size_t)s * 8192 + (kc0 + kk) * 64),
          (__attribute__((address_space(3))) unsigned int*)(ldsb + u * 1024), 16, 0, 0);
    }
  };

  const char* wbase = (const char*)wp + (size_t)(wv * 4) * 1024 + lane * 16;

  floatx4 acc[4][8];
#pragma unroll
  for (int ii = 0; ii < 4; ++ii)
#pragma unroll
    for (int j = 0; j < 8; ++j) acc[ii][j] = (floatx4){0.f, 0.f, 0.f, 0.f};

  stage2(0, phase);
  __syncthreads();

  for (int i = 0; i < 4; ++i) {
    const int kc0  = (2 * i + phase) & 7;
    const int kc0n = (2 * i + 2 + phase) & 7;
    if (i < 3) stage2((i + 1) & 1, kc0n);
    const char* bufp = (const char*)smem + (i & 1) * BUF5;
#pragma unroll
    for (int n = 0; n < 7; ++n) {
#pragma unroll
      for (int kk = 0; kk < 2; ++kk) {
        const int kc = kc0 + kk;
        short8 af[4];
#pragma unroll
        for (int ii = 0; ii < 4; ++ii)
          af[ii] = *(const short8*)(wbase + ((size_t)((n * 8 + kc) * 16 + ii)) * 1024);
        const char* bp = bufp + kk * (NSEG5 * 1024) + ba[n];
        short8 bf[8];
#pragma unroll
        for (int j = 0; j < 8; ++j)
          bf[j] = *(const short8*)(bp + j * 1024);
#pragma unroll
        for (int ii = 0; ii < 4; ++ii)
#pragma unroll
          for (int j = 0; j < 8; ++j)
            acc[ii][j] = __builtin_amdgcn_mfma_f32_16x16x32_bf16(af[ii], bf[j], acc[ii][j], 0, 0, 0);
      }
    }
    __syncthreads();
  }

  // epilogue: D[row=quad*4+rr][col]; o = wv*64+ii*16+quad*4+rr, padded pix = P0+j*16+col
  const int ob = wv * 64;
  floatx4 bv[4];
#pragma unroll
  for (int ii = 0; ii < 4; ++ii)
    bv[ii] = *(const floatx4*)(bias + ob + ii * 16 + quad * 4);

#pragma unroll
  for (int j = 0; j < 8; ++j) {
    int p = P0 + j * 16 + col;
    int h = p / W50;
    int w = p - h * W50;
    if (w >= 49 || p >= PREAL) continue;
    bool m = (h + w >= 24) && (h + w <= 72);
    size_t ridx = (size_t)h * 49 + w;
#pragma unroll
    for (int ii = 0; ii < 4; ++ii) {
      float* dst = out + ((size_t)(b * 256 + ob + ii * 16 + quad * 4)) * NPIX + ridx;
#pragma unroll
      for (int rr = 0; rr < 4; ++rr) {
        float v = m ? (acc[ii][j][rr] + bv[ii][rr]) : 0.f;
        dst[(size_t)rr * NPIX] = v;
      }
    }
  }
}

// ---------------- fallback v1 (ws too small) ----------------
#define PITCH  40
#define V1WIN  168
#define V1ZROW 168
__global__ __launch_bounds__(256)
void hexconv_v1(const float* __restrict__ x,
                const unsigned short* __restrict__ wp,
                const float* __restrict__ bias,
                float* __restrict__ out) {
  __shared__ unsigned short sm[(V1ZROW + 2) * PITCH];
  const int tid = threadIdx.x, lane = tid & 63, wv = tid >> 6;
  const int col = lane & 15, quad = lane >> 4;
  const int pt = blockIdx.x, b = blockIdx.y;
  const int P0 = pt * 64, win_start = P0 - 52;
  if (tid < PITCH * 2) sm[V1ZROW * PITCH + tid] = 0;
  const int OFF[7] = {0, 49, 1, -48, -49, -1, 48};
  const int DXP = (1 << 2) | (1 << 3), DXN = (1 << 5) | (1 << 6);
  int baddr[4][7];
#pragma unroll
  for (int j = 0; j < 4; ++j) {
    int pix = P0 + j * 16 + col;
    int wj = pix % 49;
    int rowbase = pix - win_start;
#pragma unroll
    for (int n = 0; n < 7; ++n) {
      bool bad = (((DXP >> n) & 1) && wj == 48) || (((DXN >> n) & 1) && wj == 0);
      int row = bad ? V1ZROW : (rowbase + OFF[n]);
      baddr[j][n] = row * (PITCH * 2) + quad * 16;
    }
  }
  int sp[3], sgp[3]; bool sok[3];
#pragma unroll
  for (int pi = 0; pi < 3; ++pi) {
    int p = lane + pi * 64, gp = win_start + p;
    sp[pi] = p; sgp[pi] = gp;
    bool hm = false;
    if (gp >= 0 && gp < NPIX) { int h = gp / 49, w = gp - h * 49, s = h + w; hm = (s >= 24 && s <= 72); }
    sok[pi] = (p < V1WIN) && hm;
  }
  floatx4 acc[4][4];
#pragma unroll
  for (int i = 0; i < 4; ++i)
#pragma unroll
    for (int j = 0; j < 4; ++j) acc[i][j] = (floatx4){0.f, 0.f, 0.f, 0.f};
  const short8* wpv = (const short8*)wp;
  const int wslot = wv * 4;
  for (int kc = 0; kc < 8; ++kc) {
    __syncthreads();
#pragma unroll
    for (int ci = 0; ci < 8; ++ci) {
      int c = ci * 4 + wv;
      const float* src = x + ((size_t)(b * 256 + kc * 32 + c)) * NPIX;
#pragma unroll
      for (int pi = 0; pi < 3; ++pi) {
        if (sp[pi] < V1WIN) {
          float v = sok[pi] ? src[sgp[pi]] : 0.f;
          sm[sp[pi] * PITCH + c] = f2bf(v);
        }
      }
    }
    __syncthreads();
#pragma unroll
    for (int n = 0; n < 7; ++n) {
      short8 af[4];
#pragma unroll
      for (int i = 0; i < 4; ++i)
        af[i] = wpv[((size_t)((n * 8 + kc) * 16 + wslot + i)) * 64 + lane];
      short8 bf[4];
#pragma unroll
      for (int j = 0; j < 4; ++j)
        bf[j] = *(const short8*)((const char*)sm + baddr[j][n]);
#pragma unroll
      for (int i = 0; i < 4; ++i)
#pragma unroll
        for (int j = 0; j < 4; ++j)
          acc[i][j] = __builtin_amdgcn_mfma_f32_16x16x32_bf16(af[i], bf[j], acc[i][j], 0, 0, 0);
    }
  }
  const int ob = wv * 64;
  floatx4 bv[4];
#pragma unroll
  for (int i = 0; i < 4; ++i)
    bv[i] = *(const floatx4*)(bias + ob + i * 16 + quad * 4);
#pragma unroll
  for (int j = 0; j < 4; ++j) {
    int pix = P0 + j * 16 + col;
    if (pix >= NPIX) continue;
    int h = pix / 49, w = pix - h * 49;
    bool m = (h + w >= 24 && h + w <= 72);
#pragma unroll
    for (int i = 0; i < 4; ++i) {
      int o = ob + i * 16 + quad * 4;
      float* dst = out + ((size_t)(b * 256 + o)) * NPIX + pix;
#pragma unroll
      for (int r = 0; r < 4; ++r) {
        float v = m ? (acc[i][j][r] + bv[i][r]) : 0.f;
        dst[(size_t)r * NPIX] = v;
      }
    }
  }
}

extern "C" void kernel_launch(void* const* d_in, const int* in_sizes, int n_in,
                              void* d_out, int out_size, void* d_ws, size_t ws_size,
                              hipStream_t stream) {
  const float* x    = (const float*)d_in[0];   // [32,256,49,49]
  const float* w    = (const float*)d_in[1];   // [256,256,7]
  const float* bias = (const float*)d_in[2];   // [256]
  float* out = (float*)d_out;

  if (ws_size >= WS_NEED3) {
    unsigned short* xb = (unsigned short*)d_ws;
    unsigned short* wp = (unsigned short*)((char*)d_ws + XB3_BYTES);
    zero_pads5<<<(32 * NPADROW * 32 + 255) / 256, 256, 0, stream>>>(xb);
    prep_w_kernel<<<224, 256, 0, stream>>>(w, wp);
    prep_x4<<<dim3(38, 4, 32), 256, 0, stream>>>(x, xb);
    hexconv_v5<<<dim3(NT5, 32), 256, 0, stream>>>(xb, wp, bias, out);
  } else {
    unsigned short* wp = (unsigned short*)d_ws;
    prep_w_kernel<<<224, 256, 0, stream>>>(w, wp);
    hexconv_v1<<<dim3(38, 32), 256, 0, stream>>>(x, wp, bias, out);
  }
}

// Round 6
// 233.167 us; speedup vs baseline: 1.1364x; 1.0474x over previous
//
#include <hip/hip_runtime.h>

// HexConv2d implicit GEMM, bf16 MFMA 16x16x32.
// v6: PT=160 pixels/block -> grid 16x32 = 512 = exactly 2 blocks/CU (zero packing
// tail; v5's 640/512 grid ran 2 synchronized rounds at 62.5% util). acc 4x10/wave
// (160 AGPR, VGPR capped 96 via launch_bounds(256,2)). 2-kc double-buffered
// global_load_lds stages (34KB/buf, 68KB LDS, 2 blocks/CU = 136KB), 3 barriers.
// Pitch-50 padded pixel space (all tap edge cases = natural zero reads); weights
// fragment-packed in L2. Prep: compact pad-zeroing + coalesced masked transpose.

typedef __attribute__((ext_vector_type(8))) short short8;
typedef __attribute__((ext_vector_type(4))) short short4v;
typedef __attribute__((ext_vector_type(4))) float floatx4;

#define NPIX   2401
#define W50    50
#define PREAL  2450      // 49 rows * 50
#define XBLEAD 56
#define XBROWS 2672      // padded rows per batch: [-56, 2616)
#define PT6    160       // pixels per block
#define NT6    16        // 16*160 = 2560 >= 2450 ; grid 16x32 = 512 = 2/CU exactly
#define NSEG6  17        // 272 window rows: [P0-56, P0+216)
#define BUF6   (2*NSEG6*1024)                 // 34816 B per buffer (2 kc)
#define XB3_BYTES ((size_t)32*XBROWS*256*2)   // 43,778,048
#define WP_BYTES  917504ULL
#define WS_NEED3  (XB3_BYTES + WP_BYTES)
#define NPADROW 271      // 56 apron + 49 col-49 + 166 tail rows per batch

__device__ __forceinline__ unsigned short f2bf(float f) {
  unsigned u = __builtin_bit_cast(unsigned, f);
  u += 0x7fffu + ((u >> 16) & 1u);          // RNE
  return (unsigned short)(u >> 16);
}

// ---------------- prep: W[o,c,n] fp32 -> bf16 MFMA-A fragment order ----------------
// frag f = ((n*8+kc)*16+ot): lane l holds 8 bf16: W[ot*16+(l&15)][kc*32+(l>>4)*8+j][n]
__global__ void prep_w_kernel(const float* __restrict__ w, unsigned short* __restrict__ wp) {
  int t = blockIdx.x * 256 + threadIdx.x;   // 0..57343
  int l  = t & 63;
  int ot = (t >> 6) & 15;
  int kc = (t >> 10) & 7;
  int n  = t >> 13;
  int o  = ot * 16 + (l & 15);
  int cb = kc * 32 + ((l >> 4) * 8);
  const float* src = w + (size_t)(o * 256 + cb) * 7 + n;
  short8 pk;
#pragma unroll
  for (int j = 0; j < 8; ++j) pk[j] = (short)f2bf(src[j * 7]);
  ((short8*)wp)[t] = pk;
}

// ---------------- prep: zero only the pad rows of xb (compact) ----------------
__global__ void zero_pads5(unsigned short* __restrict__ xb) {
  int idx = blockIdx.x * 256 + threadIdx.x;   // 32*271*32 = 277,504 threads
  if (idx >= 32 * NPADROW * 32) return;
  int c16 = idx & 31;
  int rr  = idx >> 5;
  int pr  = rr % NPADROW;
  int b   = rr / NPADROW;
  int row;
  if (pr < 56)        row = pr;                          // leading apron
  else if (pr < 105)  row = 105 + 50 * (pr - 56);        // col-49 pad rows
  else                row = 2506 + (pr - 105);           // trailing apron
  short8 z = {0,0,0,0,0,0,0,0};
  *(short8*)(xb + ((size_t)b * XBROWS + row) * 256 + c16 * 8) = z;
}

// ---------------- prep: x [b][c][2401] fp32 -> xb [b][row][256c] bf16 (masked) ------
__global__ __launch_bounds__(256)
void prep_x4(const float* __restrict__ x, unsigned short* __restrict__ xb) {
  __shared__ unsigned short t[64][68];      // [ch_local][pix_local]
  const int tid = threadIdx.x;
  const int span = blockIdx.x, cg = blockIdx.y, b = blockIdx.z;
  const int s0 = span * 64;
  {
    const int chl = tid >> 2, i4 = tid & 3;
    const float* src = x + ((size_t)(b * 256 + cg * 64 + chl)) * NPIX;
    const int rbase = s0 + i4 * 16;
#pragma unroll
    for (int it = 0; it < 4; ++it) {
      int r = rbase + it * 4;
      float vv[4] = {0.f, 0.f, 0.f, 0.f};
      if (r + 3 < NPIX) {
        float4 v = *(const float4*)(src + r);
        vv[0] = v.x; vv[1] = v.y; vv[2] = v.z; vv[3] = v.w;
      } else {
#pragma unroll
        for (int e = 0; e < 4; ++e) if (r + e < NPIX) vv[e] = src[r + e];
      }
      short4v u = {0, 0, 0, 0};
#pragma unroll
      for (int e = 0; e < 4; ++e) {
        int re = r + e;
        unsigned short uu = 0;
        if (re < NPIX) {
          int h = re / 49, w = re - h * 49, s = h + w;
          if (s >= 24 && s <= 72) uu = f2bf(vv[e]);
        }
        u[e] = (short)uu;
      }
      *(short4v*)&t[chl][i4 * 16 + it * 4] = u;
    }
  }
  __syncthreads();
  const int pp = tid >> 3;   // pixel pair 0..31
  const int co = tid & 7;    // channel octet 0..7
  unsigned d[8];
#pragma unroll
  for (int k = 0; k < 8; ++k) d[k] = *(const unsigned*)&t[co * 8 + k][pp * 2];
  uint4 lo, hi;
  {
    unsigned l0[4], h0[4];
#pragma unroll
    for (int m = 0; m < 4; ++m) {
      unsigned a = d[2 * m], bq = d[2 * m + 1];
      l0[m] = (a & 0xffffu) | (bq << 16);
      h0[m] = (a >> 16) | (bq & 0xffff0000u);
    }
    lo = make_uint4(l0[0], l0[1], l0[2], l0[3]);
    hi = make_uint4(h0[0], h0[1], h0[2], h0[3]);
  }
  const int r_lo = s0 + pp * 2, r_hi = r_lo + 1;
  if (r_lo < NPIX) {
    int prow = r_lo + r_lo / 49 + XBLEAD;
    *(uint4*)(xb + ((size_t)b * XBROWS + prow) * 256 + cg * 64 + co * 8) = lo;
  }
  if (r_hi < NPIX) {
    int prow = r_hi + r_hi / 49 + XBLEAD;
    *(uint4*)(xb + ((size_t)b * XBROWS + prow) * 256 + cg * 64 + co * 8) = hi;
  }
}

// ---------------- main v6 ----------------
__global__ __launch_bounds__(256, 2)
void hexconv_v6(const unsigned short* __restrict__ xb,
                const unsigned short* __restrict__ wp,
                const float* __restrict__ bias,
                float* __restrict__ out) {
  __shared__ __attribute__((aligned(16))) unsigned char smem[2 * BUF6];  // 69632 B

  const int tid  = threadIdx.x;
  const int lane = tid & 63;
  const int wv   = tid >> 6;
  const int col  = lane & 15;
  const int quad = lane >> 4;

  const int pt = blockIdx.x;          // 0..15
  const int b  = blockIdx.y;
  const int P0 = pt * PT6;
  const int phase = ((pt + b) & 3) * 2;

  // tap offsets in pitch-50 padded space
  const int OFF[7] = {0, 50, 1, -49, -50, -1, 49};

  // B-frag LDS base addresses (kc/j-invariant; j adds j*1024 = 16 rows)
  int ba[7];
#pragma unroll
  for (int n = 0; n < 7; ++n) {
    int r0 = col + 56 + OFF[n];              // 6..121
    int r64 = r0 << 6;
    ba[n] = (r64 + quad * 16) ^ ((r64 >> 3) & 0x30);
  }

  // staging: within a seg, lane l covers row 16s+(l>>2), LDS part l&3 (HW-forced),
  // global part swizzled so compute-side XOR lands conflict-free
  const int gpart = (lane & 3) ^ ((lane >> 3) & 3);
  const char* gsrc0 = (const char*)(xb + ((size_t)b * XBROWS + (size_t)P0) * 256)
                      + (lane >> 2) * 512 + gpart * 16;

  // stage 2 kc into one buffer: 34 seg-units split over 4 waves
  auto stage2 = [&](int buf, int kc0) {
    char* ldsb = (char*)smem + buf * BUF6;
    for (int u = wv; u < 2 * NSEG6; u += 4) {
      int kk = (u >= NSEG6) ? 1 : 0;
      int s  = u - kk * NSEG6;
      __builtin_amdgcn_global_load_lds(
          (const __attribute__((address_space(1))) unsigned int*)
              (gsrc0 + (size_t)s * 8192 + (kc0 + kk) * 64),
          (__attribute__((address_space(3))) unsigned int*)(ldsb + u * 1024), 16, 0, 0);
    }
  };

  const char* wbase = (const char*)wp + (size_t)(wv * 4) * 1024 + lane * 16;

  floatx4 acc[4][10];
#pragma unroll
  for (int ii = 0; ii < 4; ++ii)
#pragma unroll
    for (int j = 0; j < 10; ++j) acc[ii][j] = (floatx4){0.f, 0.f, 0.f, 0.f};

  stage2(0, phase);
  __syncthreads();

  for (int i = 0; i < 4; ++i) {
    const int kc0  = (2 * i + phase) & 7;
    const int kc0n = (2 * i + 2 + phase) & 7;
    if (i < 3) stage2((i + 1) & 1, kc0n);
    const char* bufp = (const char*)smem + (i & 1) * BUF6;
#pragma unroll
    for (int n = 0; n < 7; ++n) {
#pragma unroll
      for (int kk = 0; kk < 2; ++kk) {
        const int kc = kc0 + kk;
        short8 af[4];
#pragma unroll
        for (int ii = 0; ii < 4; ++ii)
          af[ii] = *(const short8*)(wbase + ((size_t)((n * 8 + kc) * 16 + ii)) * 1024);
        const char* bp = bufp + kk * (NSEG6 * 1024) + ba[n];
#pragma unroll
        for (int j = 0; j < 10; ++j) {
          short8 bf = *(const short8*)(bp + j * 1024);
#pragma unroll
          for (int ii = 0; ii < 4; ++ii)
            acc[ii][j] = __builtin_amdgcn_mfma_f32_16x16x32_bf16(af[ii], bf, acc[ii][j], 0, 0, 0);
        }
      }
    }
    if (i < 3) __syncthreads();
  }

  // epilogue: D[row=quad*4+rr][col]; o = wv*64+ii*16+quad*4+rr, padded pix = P0+j*16+col
  const int ob = wv * 64;
  floatx4 bv[4];
#pragma unroll
  for (int ii = 0; ii < 4; ++ii)
    bv[ii] = *(const floatx4*)(bias + ob + ii * 16 + quad * 4);

#pragma unroll
  for (int j = 0; j < 10; ++j) {
    int p = P0 + j * 16 + col;
    int h = p / W50;
    int w = p - h * W50;
    if (w >= 49 || p >= PREAL) continue;
    bool m = (h + w >= 24) && (h + w <= 72);
    size_t ridx = (size_t)h * 49 + w;
#pragma unroll
    for (int ii = 0; ii < 4; ++ii) {
      float* dst = out + ((size_t)(b * 256 + ob + ii * 16 + quad * 4)) * NPIX + ridx;
#pragma unroll
      for (int rr = 0; rr < 4; ++rr) {
        float v = m ? (acc[ii][j][rr] + bv[ii][rr]) : 0.f;
        dst[(size_t)rr * NPIX] = v;
      }
    }
  }
}

// ---------------- fallback v1 (ws too small) ----------------
#define PITCH  40
#define V1WIN  168
#define V1ZROW 168
__global__ __launch_bounds__(256)
void hexconv_v1(const float* __restrict__ x,
                const unsigned short* __restrict__ wp,
                const float* __restrict__ bias,
                float* __restrict__ out) {
  __shared__ unsigned short sm[(V1ZROW + 2) * PITCH];
  const int tid = threadIdx.x, lane = tid & 63, wv = tid >> 6;
  const int col = lane & 15, quad = lane >> 4;
  const int pt = blockIdx.x, b = blockIdx.y;
  const int P0 = pt * 64, win_start = P0 - 52;
  if (tid < PITCH * 2) sm[V1ZROW * PITCH + tid] = 0;
  const int OFF[7] = {0, 49, 1, -48, -49, -1, 48};
  const int DXP = (1 << 2) | (1 << 3), DXN = (1 << 5) | (1 << 6);
  int baddr[4][7];
#pragma unroll
  for (int j = 0; j < 4; ++j) {
    int pix = P0 + j * 16 + col;
    int wj = pix % 49;
    int rowbase = pix - win_start;
#pragma unroll
    for (int n = 0; n < 7; ++n) {
      bool bad = (((DXP >> n) & 1) && wj == 48) || (((DXN >> n) & 1) && wj == 0);
      int row = bad ? V1ZROW : (rowbase + OFF[n]);
      baddr[j][n] = row * (PITCH * 2) + quad * 16;
    }
  }
  int sp[3], sgp[3]; bool sok[3];
#pragma unroll
  for (int pi = 0; pi < 3; ++pi) {
    int p = lane + pi * 64, gp = win_start + p;
    sp[pi] = p; sgp[pi] = gp;
    bool hm = false;
    if (gp >= 0 && gp < NPIX) { int h = gp / 49, w = gp - h * 49, s = h + w; hm = (s >= 24 && s <= 72); }
    sok[pi] = (p < V1WIN) && hm;
  }
  floatx4 acc[4][4];
#pragma unroll
  for (int i = 0; i < 4; ++i)
#pragma unroll
    for (int j = 0; j < 4; ++j) acc[i][j] = (floatx4){0.f, 0.f, 0.f, 0.f};
  const short8* wpv = (const short8*)wp;
  const int wslot = wv * 4;
  for (int kc = 0; kc < 8; ++kc) {
    __syncthreads();
#pragma unroll
    for (int ci = 0; ci < 8; ++ci) {
      int c = ci * 4 + wv;
      const float* src = x + ((size_t)(b * 256 + kc * 32 + c)) * NPIX;
#pragma unroll
      for (int pi = 0; pi < 3; ++pi) {
        if (sp[pi] < V1WIN) {
          float v = sok[pi] ? src[sgp[pi]] : 0.f;
          sm[sp[pi] * PITCH + c] = f2bf(v);
        }
      }
    }
    __syncthreads();
#pragma unroll
    for (int n = 0; n < 7; ++n) {
      short8 af[4];
#pragma unroll
      for (int i = 0; i < 4; ++i)
        af[i] = wpv[((size_t)((n * 8 + kc) * 16 + wslot + i)) * 64 + lane];
      short8 bf[4];
#pragma unroll
      for (int j = 0; j < 4; ++j)
        bf[j] = *(const short8*)((const char*)sm + baddr[j][n]);
#pragma unroll
      for (int i = 0; i < 4; ++i)
#pragma unroll
        for (int j = 0; j < 4; ++j)
          acc[i][j] = __builtin_amdgcn_mfma_f32_16x16x32_bf16(af[i], bf[j], acc[i][j], 0, 0, 0);
    }
  }
  const int ob = wv * 64;
  floatx4 bv[4];
#pragma unroll
  for (int i = 0; i < 4; ++i)
    bv[i] = *(const floatx4*)(bias + ob + i * 16 + quad * 4);
#pragma unroll
  for (int j = 0; j < 4; ++j) {
    int pix = P0 + j * 16 + col;
    if (pix >= NPIX) continue;
    int h = pix / 49, w = pix - h * 49;
    bool m = (h + w >= 24 && h + w <= 72);
#pragma unroll
    for (int i = 0; i < 4; ++i) {
      int o = ob + i * 16 + quad * 4;
      float* dst = out + ((size_t)(b * 256 + o)) * NPIX + pix;
#pragma unroll
      for (int r = 0; r < 4; ++r) {
        float v = m ? (acc[i][j][r] + bv[i][r]) : 0.f;
        dst[(size_t)r * NPIX] = v;
      }
    }
  }
}

extern "C" void kernel_launch(void* const* d_in, const int* in_sizes, int n_in,
                              void* d_out, int out_size, void* d_ws, size_t ws_size,
                              hipStream_t stream) {
  const float* x    = (const float*)d_in[0];   // [32,256,49,49]
  const float* w    = (const float*)d_in[1];   // [256,256,7]
  const float* bias = (const float*)d_in[2];   // [256]
  float* out = (float*)d_out;

  if (ws_size >= WS_NEED3) {
    unsigned short* xb = (unsigned short*)d_ws;
    unsigned short* wp = (unsigned short*)((char*)d_ws + XB3_BYTES);
    zero_pads5<<<(32 * NPADROW * 32 + 255) / 256, 256, 0, stream>>>(xb);
    prep_w_kernel<<<224, 256, 0, stream>>>(w, wp);
    prep_x4<<<dim3(38, 4, 32), 256, 0, stream>>>(x, xb);
    hexconv_v6<<<dim3(NT6, 32), 256, 0, stream>>>(xb, wp, bias, out);
  } else {
    unsigned short* wp = (unsigned short*)d_ws;
    prep_w_kernel<<<224, 256, 0, stream>>>(w, wp);
    hexconv_v1<<<dim3(38, 32), 256, 0, stream>>>(x, wp, bias, out);
  }
}